// Round 15
// baseline (88.808 us; speedup 1.0000x reference)
//
#include <hip/hip_runtime.h>

#define VOCAB 4096
#define SLICES 16
#define SLICE 256            // codes per slice (16-way split per point-set)
#define GRP 8                // codes per max-tree group
#define NGRP (SLICE / GRP)   // 32 groups per slice
#define P 4                  // points per lane
#define PTS (64 * P)         // 256 points per block
#define THREADS 1024

// Empty-asm register barrier: forces the value into a VGPR, preventing
// fma-contraction / reassociation across it. Emits no instruction.
__device__ __forceinline__ float opaque(float x) {
  asm volatile("" : "+v"(x));
  return x;
}

// v_max3_f32: value-identical to nested fmaxf for finite inputs (max is
// exact). Compiler won't form max3 without nnan, so emit directly.
__device__ __forceinline__ float max3f(float a, float b, float c) {
  float d;
  asm("v_max3_f32 %0, %1, %2, %3" : "=v"(d) : "v"(a), "v"(b), "v"(c));
  return d;
}

// v_med3_f32: with invariant t2 <= t1 (maintained by the scan) and finite
// gm, med3(t2, t1, gm) == max(t2, min(t1, gm)) — the streaming top-2
// update in ONE instruction (exact: no rounding in min/max/median).
__device__ __forceinline__ float med3f(float a, float b, float c) {
  float d;
  asm("v_med3_f32 %0, %1, %2, %3" : "=v"(d) : "v"(a), "v"(b), "v"(c));
  return d;
}

// Surrogate scan value: t = x.e - c/2 (3 fma). Exact relation: a - 2T = D.
__device__ __forceinline__ float tval(float x0, float x1, float x2,
                                      float4 cd) {
  return fmaf(x0, cd.x, fmaf(x1, cd.y, fmaf(x2, cd.z, cd.w)));
}

// Bit-exact numpy f32 distance (validated absmax=0.0 R10/R12/R13/R14):
//   m = x.e (fma ascending k, first term single-rounded mul)
//   d = (a - 2m) + c;  c = -2*h exact (fma-contract-safe).
__device__ __forceinline__ float dist_f32(float x0, float x1, float x2,
                                          float a, float4 cd) {
  float m = fmaf(x2, cd.z, fmaf(x1, cd.y, x0 * cd.x));
  return fmaf(-2.0f, m, a) + (-2.0f * cd.w);
}

// Single fused kernel: 256 blocks x 1024 threads; block = 256 points
// (4/lane) x 16 slices. Codebook staged+prepped inline in LDS (~117 KB,
// 1 block/CU = 16 waves = 4/SIMD). Surrogate scan; margin-certified 8-code
// exact rescan; bounded cooperative bit-exact fallback.
__global__ __launch_bounds__(THREADS) void vq_kernel(
    const float* __restrict__ feats, const float* __restrict__ cb,
    float* __restrict__ out_quant, float* __restrict__ out_idx,
    float* __restrict__ out_loss, int npts) {
  __shared__ float4 sTab[VOCAB];            // 64 KB staged codebook
  __shared__ float sT1[SLICES * PTS];       // 16 KB per-slice best t
  __shared__ float sT2[SLICES * PTS];       // 16 KB per-slice 2nd-best
  __shared__ int sG[SLICES * PTS];          // 16 KB per-slice group base
  __shared__ unsigned long long sSlot[PTS]; // 2 KB fallback (d,idx) keys
  __shared__ int sList[PTS];                // 1 KB flagged point ids
  __shared__ int sCount;
  __shared__ double sL[PTS];                // 2 KB loss partials

  const int tid = threadIdx.x;
  const int lane = tid & 63;
  const int s = tid >> 6;                   // slice id 0..15 (wave-uniform)

  if (tid == 0) sCount = 0;

  // Stage + prep codebook inline (prep kernel folded in): per code compute
  // h = -0.5f*c with c = ((e0*e0+e1*e1)+e2*e2), each product/sum rounded
  // f32 exactly like numpy (opaque barriers). Bit-identical to the old
  // vq_prep_kernel table (validated R10-R14: absmax 0.0).
#pragma unroll
  for (int k = 0; k < VOCAB / THREADS; ++k) {
    int j = tid + k * THREADS;
    float e0 = cb[3 * j + 0];
    float e1 = cb[3 * j + 1];
    float e2 = cb[3 * j + 2];
    float p0 = opaque(e0 * e0);
    float p1 = opaque(e1 * e1);
    float p2 = opaque(e2 * e2);
    float c = opaque(opaque(p0 + p1) + p2);
    sTab[j] = make_float4(e0, e1, e2, -0.5f * c);
  }

  const int pbase = blockIdx.x * PTS;
  // Lane's P points: pbase + k*64 + lane, k = 0..P-1 (same for all waves).
  float px[P], py[P], pz[P], nn[P];
#pragma unroll
  for (int k = 0; k < P; ++k) {
    const int p = pbase + k * 64 + lane;
    px[k] = feats[3 * p + 0];
    py[k] = feats[3 * p + 1];
    pz[k] = feats[3 * p + 2];
    // ||x||^2 exactly as numpy: products rounded, then ((p0+p1)+p2)
    float q0 = opaque(px[k] * px[k]);
    float q1 = opaque(py[k] * py[k]);
    float q2 = opaque(pz[k] * pz[k]);
    nn[k] = opaque(opaque(q0 + q1) + q2);
  }

  __syncthreads();  // staging complete

  const float4* cs = sTab + s * SLICE;

  // Phase 1: surrogate max-scan, P points per lane, codes via LDS broadcast.
  float t1[P], t2[P];
  int gg[P];
#pragma unroll
  for (int k = 0; k < P; ++k) { t1[k] = -3.4e38f; t2[k] = -3.4e38f; gg[k] = 0; }
#pragma unroll 2
  for (int g = 0; g < NGRP; ++g) {
    const float4* gp = cs + g * GRP;  // same addr all lanes -> broadcast
    float4 c0 = gp[0], c1 = gp[1], c2 = gp[2], c3 = gp[3];
    float4 c4 = gp[4], c5 = gp[5], c6 = gp[6], c7 = gp[7];
#pragma unroll
    for (int k = 0; k < P; ++k) {
      float u0 = tval(px[k], py[k], pz[k], c0);
      float u1 = tval(px[k], py[k], pz[k], c1);
      float u2 = tval(px[k], py[k], pz[k], c2);
      float u3 = tval(px[k], py[k], pz[k], c3);
      float u4 = tval(px[k], py[k], pz[k], c4);
      float u5 = tval(px[k], py[k], pz[k], c5);
      float u6 = tval(px[k], py[k], pz[k], c6);
      float u7 = tval(px[k], py[k], pz[k], c7);
      float gm = max3f(max3f(u0, u1, u2), max3f(u3, u4, u5), fmaxf(u6, u7));
      t2[k] = med3f(t2[k], t1[k], gm);         // streaming top-2 (1 inst)
      if (gm > t1[k]) gg[k] = g;               // strict >: earliest group
      t1[k] = fmaxf(t1[k], gm);
    }
  }
#pragma unroll
  for (int k = 0; k < P; ++k) {
    sT1[s * PTS + k * 64 + lane] = t1[k];
    sT2[s * PTS + k * 64 + lane] = t2[k];
    sG[s * PTS + k * 64 + lane] = s * SLICE + gg[k] * GRP;
  }
  __syncthreads();

  // Epilogue combine: tid < 256 owns block-point pt == tid; its coords are
  // its own registers' point k == s (waves 0..3 cover tid 0..255).
  int bi = 0;
  float q0 = 0.0f, q1 = 0.0f, q2 = 0.0f;
  bool flagged = false;
  float x0 = px[0], x1 = py[0], x2 = pz[0], a = nn[0];
#pragma unroll
  for (int k = 1; k < P; ++k) {
    if (s == k) { x0 = px[k]; x1 = py[k]; x2 = pz[k]; a = nn[k]; }
  }
  if (tid < PTS) {
    float b1 = sT1[tid], b2 = sT2[tid];
    int gbase = sG[tid];
#pragma unroll
    for (int k = 1; k < SLICES; ++k) {  // ascending slice order
      float u1 = sT1[k * PTS + tid];
      float u2 = sT2[k * PTS + tid];
      b2 = fmaxf(fmaxf(b2, u2), fminf(b1, u1));
      if (u1 > b1) gbase = sG[k * PTS + tid];
      b1 = fmaxf(b1, u1);
    }
    // Margin test (validated R10/R12-R14): if best group's t beats every
    // other group's max by more than worst-case surrogate-vs-numpy skew,
    // ref argmin is inside gbase. eps = a*2^-21 + 2^-20 (2x safe).
    float eps = fmaf(a, 0x1p-21f, 0x1p-20f);
    flagged = !((b1 - b2) > eps);
    if (flagged) {
      int pos = atomicAdd(&sCount, 1);
      sList[pos] = tid;
      sSlot[tid] = ~0ULL;
    } else {
      // Bit-exact rescan of the certified 8-code group (from LDS copy);
      // ascending, strict <: np.argmin first-occurrence.
      float bd = 3.4e38f;
#pragma unroll
      for (int k = 0; k < GRP; ++k) {
        float4 cd = sTab[gbase + k];
        float d = dist_f32(x0, x1, x2, a, cd);
        if (d < bd) { bd = d; bi = gbase + k; q0 = cd.x; q1 = cd.y; q2 = cd.z; }
      }
    }
  }
  __syncthreads();

  // Phase 2: cooperative bit-exact full rescan for flagged points.
  // 1024 threads x 4 codes each; sortable (d,idx) key min-reduce: min key
  // == min d, tie -> min idx (first occurrence).
  const int cnt = sCount;
  for (int f = 0; f < cnt; ++f) {
    const int fpt = sList[f];
    const int fp = pbase + fpt;
    float y0 = feats[3 * fp + 0];   // same addr all threads -> broadcast
    float y1 = feats[3 * fp + 1];
    float y2 = feats[3 * fp + 2];
    float yp0 = opaque(y0 * y0);
    float yp1 = opaque(y1 * y1);
    float yp2 = opaque(y2 * y2);
    float ay = opaque(opaque(yp0 + yp1) + yp2);
    float bd = 3.4e38f;
    int bj = 0;
#pragma unroll
    for (int k = 0; k < VOCAB / THREADS; ++k) {
      int j = tid + k * THREADS;
      float4 cd = sTab[j];
      float d = dist_f32(y0, y1, y2, ay, cd);
      if (d < bd) { bd = d; bj = j; }
    }
    unsigned b = __float_as_uint(bd);
    b = (b & 0x80000000u) ? ~b : (b | 0x80000000u);  // total-order transform
    unsigned long long key = ((unsigned long long)b << 32) | (unsigned)bj;
#pragma unroll
    for (int off = 1; off < 64; off <<= 1) {         // wave min-butterfly
      unsigned long long o = __shfl_xor(key, off);
      key = (o < key) ? o : key;
    }
    if (lane == 0) atomicMin(&sSlot[fpt], key);      // 16 atomics/point
  }
  __syncthreads();

  if (tid < PTS) {
    if (flagged) {
      bi = (int)(unsigned)(sSlot[tid] & 0xFFFFFFFFu);
      float4 cd = sTab[bi];
      q0 = cd.x; q1 = cd.y; q2 = cd.z;
    }
    const int p = pbase + tid;
    // straight-through: t = q - x (f32), out = x + t (f32), like reference
    float t0 = q0 - x0, t1d = q1 - x1, t2d = q2 - x2;
    out_quant[3 * p + 0] = x0 + t0;
    out_quant[3 * p + 1] = x1 + t1d;
    out_quant[3 * p + 2] = x2 + t2d;
    out_idx[p] = (float)bi;
    sL[tid] = (double)t0 * t0 + (double)t1d * t1d + (double)t2d * t2d;
  }
  __syncthreads();

  if (tid == 0) {
    double acc = 0.0;
#pragma unroll 8
    for (int k = 0; k < PTS; ++k) acc += sL[k];
    // loss = mean((q-x)^2) + 0.25*mean((x-q)^2) = 1.25 * sum / (npts*3)
    atomicAdd(out_loss, (float)(acc * (1.25 / ((double)npts * 3.0))));
  }
}

extern "C" void kernel_launch(void* const* d_in, const int* in_sizes, int n_in,
                              void* d_out, int out_size, void* d_ws,
                              size_t ws_size, hipStream_t stream) {
  const float* feats = (const float*)d_in[0];      // (B*L, 3) f32
  const float* cb = (const float*)d_in[1];         // (4096, 3) f32
  const int npts = in_sizes[0] / 3;                // 65536

  float* out = (float*)d_out;
  float* out_quant = out;                          // npts*3 elems
  float* out_idx = out + in_sizes[0];              // npts elems
  float* out_loss = out + in_sizes[0] + npts;      // 1 elem

  // Zero the loss accumulator (stream-ordered before the kernel's atomics).
  hipMemsetAsync(out_loss, 0, sizeof(float), stream);
  vq_kernel<<<npts / PTS, THREADS, 0, stream>>>(feats, cb, out_quant, out_idx,
                                                out_loss, npts);
}